// Round 1
// baseline (266.550 us; speedup 1.0000x reference)
//
#include <hip/hip_runtime.h>
#include <stdint.h>

#define TT 512   // max sequence length (T)
#define KK 5     // number of tags

// ---------------------------------------------------------------------------
// Kernel 0: counting sort of batch indices by sequence length.
// Lets waves process similar-length batches -> early exit actually pays.
// Single block, 512 threads. Output order[] is a permutation of 0..B-1.
// ---------------------------------------------------------------------------
__global__ void sort_by_len_kernel(const int* __restrict__ lens,
                                   int* __restrict__ order, int B) {
  __shared__ int hist[TT + 1];
  const int tid = threadIdx.x;
  for (int i = tid; i <= TT; i += blockDim.x) hist[i] = 0;
  __syncthreads();
  for (int b = tid; b < B; b += blockDim.x) atomicAdd(&hist[lens[b]], 1);
  __syncthreads();
  if (tid == 0) {
    int acc = 0;
    for (int i = 1; i <= TT; ++i) { int c = hist[i]; hist[i] = acc; acc += c; }
  }
  __syncthreads();
  for (int b = tid; b < B; b += blockDim.x) {
    int p = atomicAdd(&hist[lens[b]], 1);
    order[p] = b;
  }
}

// ---------------------------------------------------------------------------
// Kernel 1: zero-fill the decoded region (positions >= len must be 0; the
// scan kernel only writes t < len).
// ---------------------------------------------------------------------------
__global__ void fill_zero4_kernel(float4* __restrict__ out, size_t n4) {
  size_t i = (size_t)blockIdx.x * blockDim.x + threadIdx.x;
  const size_t stride = (size_t)gridDim.x * blockDim.x;
  const float4 z = make_float4(0.f, 0.f, 0.f, 0.f);
  for (; i < n4; i += stride) out[i] = z;
}

// ---------------------------------------------------------------------------
// Kernel 2: fused CRF scan. One thread per batch element, wave-specialized:
//   role 0 (even blocks): Viterbi max-plus scan + backpointers + backtrace
//   role 1 (odd blocks) : forward logsumexp scan + unary/binary score
// Output layout (all float32): [0, B*T) decoded, [B*T, B*T+B) log_likelihood.
// ---------------------------------------------------------------------------
__launch_bounds__(64)
__global__ void crf_scan_kernel(const float* __restrict__ pot,
                                const float* __restrict__ trans,
                                const int* __restrict__ lens,
                                const int* __restrict__ tags,
                                const int* __restrict__ order,
                                float* __restrict__ out,
                                unsigned short* __restrict__ bp,
                                int B, int T) {
  const int gx   = blockIdx.x;
  const int role = gx & 1;
  const int grp  = gx >> 1;
  const int idx  = grp * 64 + threadIdx.x;
  if (idx >= B) return;
  const int b   = order[idx];
  const int len = lens[b];
  const float* __restrict__ prow = pot + (size_t)b * T * KK;

  float tr[KK][KK];
#pragma unroll
  for (int i = 0; i < KK; ++i)
#pragma unroll
    for (int j = 0; j < KK; ++j) tr[i][j] = trans[i * KK + j];

  if (role == 0) {
    // ---------------- Viterbi ----------------
    float a[KK];
#pragma unroll
    for (int j = 0; j < KK; ++j) a[j] = prow[j];
    unsigned short* __restrict__ bpb = bp + (size_t)b * T;
    for (int t = 1; t < len; ++t) {
      const float* p = prow + t * KK;
      float pv[KK];
#pragma unroll
      for (int j = 0; j < KK; ++j) pv[j] = p[j];
      float na[KK];
      unsigned bits = 0;
#pragma unroll
      for (int j = 0; j < KK; ++j) {
        float best = a[0] + tr[0][j];
        int bi = 0;
#pragma unroll
        for (int i = 1; i < KK; ++i) {
          float s = a[i] + tr[i][j];
          if (s > best) { best = s; bi = i; }  // strict > == jnp.argmax first-max
        }
        na[j] = best + pv[j];
        bits |= (unsigned)bi << (3 * j);
      }
#pragma unroll
      for (int j = 0; j < KK; ++j) a[j] = na[j];
      bpb[t] = (unsigned short)bits;
    }
    int last = 0;
    float bv = a[0];
#pragma unroll
    for (int i = 1; i < KK; ++i)
      if (a[i] > bv) { bv = a[i]; last = i; }
    // ---------------- backtrace ----------------
    float* __restrict__ orow = out + (size_t)b * T;
    int tag = last;
    orow[len - 1] = (float)last;
    for (int t = len - 1; t >= 1; --t) {
      int pv = (bpb[t] >> (3 * tag)) & 7;
      orow[t - 1] = (float)pv;
      tag = pv;
    }
  } else {
    // ---------------- forward logsumexp + scores ----------------
    float W[KK][KK];
#pragma unroll
    for (int i = 0; i < KK; ++i)
#pragma unroll
      for (int j = 0; j < KK; ++j) W[i][j] = __expf(tr[i][j]);
    float a[KK];
#pragma unroll
    for (int j = 0; j < KK; ++j) a[j] = prow[j];
    const int* __restrict__ tg = tags + (size_t)b * T;
    int pt = tg[0];
    float unary  = prow[pt];   // global load: avoids dynamic register indexing
    float binary = 0.0f;
    for (int t = 1; t < len; ++t) {
      const float* p = prow + t * KK;
      float pv[KK];
#pragma unroll
      for (int j = 0; j < KK; ++j) pv[j] = p[j];
      float m = a[0];
#pragma unroll
      for (int i = 1; i < KK; ++i) m = fmaxf(m, a[i]);
      float e[KK];
#pragma unroll
      for (int i = 0; i < KK; ++i) e[i] = __expf(a[i] - m);
#pragma unroll
      for (int j = 0; j < KK; ++j) {
        float s = 0.0f;
#pragma unroll
        for (int i = 0; i < KK; ++i) s += e[i] * W[i][j];
        a[j] = m + __logf(s) + pv[j];
      }
      const int ct = tg[t];
      unary  += p[ct];                  // L1 hit (line just loaded)
      binary += trans[pt * KK + ct];    // 100 B table, L1 hit
      pt = ct;
    }
    float m = a[0];
#pragma unroll
    for (int i = 1; i < KK; ++i) m = fmaxf(m, a[i]);
    float s = 0.0f;
#pragma unroll
    for (int i = 0; i < KK; ++i) s += __expf(a[i] - m);
    const float log_norm = m + __logf(s);
    out[(size_t)B * T + b] = unary + binary - log_norm;
  }
}

// ---------------------------------------------------------------------------
extern "C" void kernel_launch(void* const* d_in, const int* in_sizes, int n_in,
                              void* d_out, int out_size, void* d_ws, size_t ws_size,
                              hipStream_t stream) {
  const float* pot   = (const float*)d_in[0];
  const float* trans = (const float*)d_in[1];
  const int*   lens  = (const int*)d_in[2];
  const int*   tags  = (const int*)d_in[3];
  float* out = (float*)d_out;

  const int B = in_sizes[2];
  const int T = in_sizes[3] / B;   // 512

  unsigned short* bp = (unsigned short*)d_ws;
  int* order = (int*)((char*)d_ws + (size_t)B * T * sizeof(unsigned short));

  sort_by_len_kernel<<<1, 512, 0, stream>>>(lens, order, B);

  const size_t n4 = (size_t)B * T / 4;
  fill_zero4_kernel<<<1024, 256, 0, stream>>>((float4*)out, n4);

  const int nblocks = 2 * ((B + 63) / 64);
  crf_scan_kernel<<<nblocks, 64, 0, stream>>>(pot, trans, lens, tags, order,
                                              out, bp, B, T);
}

// Round 2
// 182.693 us; speedup vs baseline: 1.4590x; 1.4590x over previous
//
#include <hip/hip_runtime.h>
#include <stdint.h>

#define KK 5
#define BS 8

struct Blk { float4 q[10]; };        // 8 steps x 5 floats
struct TBlk { int4 lo, hi; };        // 8 tags

__device__ __forceinline__ float elt(const Blk& bb, int k) {
  const float4 v = bb.q[k >> 2];
  const int m = k & 3;
  return m == 0 ? v.x : (m == 1 ? v.y : (m == 2 ? v.z : v.w));
}
__device__ __forceinline__ int telt(const TBlk& tb, int s) {
  const int4 v = (s < 4) ? tb.lo : tb.hi;
  const int m = s & 3;
  return m == 0 ? v.x : (m == 1 ? v.y : (m == 2 ? v.z : v.w));
}
__device__ __forceinline__ void loadBlk(Blk& dst, const float4* __restrict__ src) {
#pragma unroll
  for (int q = 0; q < 10; ++q) dst.q[q] = src[q];
}
__device__ __forceinline__ void loadTBlk(TBlk& dst, const int* __restrict__ tg, int blk8) {
  dst.lo = *(const int4*)(tg + blk8);
  dst.hi = *(const int4*)(tg + blk8 + 4);
}

// ---------------- Viterbi: one 8-step block ----------------
__device__ __forceinline__ void vit_block(const Blk& X, int blk, int len,
                                          const float (&tr)[KK][KK],
                                          float (&a)[KK],
                                          uint16_t* __restrict__ bpb) {
  const int blk8 = blk * BS;
  uint32_t w[4] = {0u, 0u, 0u, 0u};
#pragma unroll
  for (int s = 0; s < BS; ++s) {
    const int t = blk8 + s;
    if (s == 0 && blk == 0) {
#pragma unroll
      for (int j = 0; j < KK; ++j) a[j] = elt(X, j);
    } else if (t < len) {
      float nv[KK];
      uint32_t bits = 0;
#pragma unroll
      for (int j = 0; j < KK; ++j) {
        const float s0 = a[0] + tr[0][j];
        const float s1 = a[1] + tr[1][j];
        const float s2 = a[2] + tr[2][j];
        const float s3 = a[3] + tr[3][j];
        const float s4 = a[4] + tr[4][j];
        const float bm = fmaxf(fmaxf(fmaxf(s0, s1), fmaxf(s2, s3)), s4);
        int bi = 4;                       // first-max tie-break (== jnp.argmax)
        bi = (s3 == bm) ? 3 : bi;
        bi = (s2 == bm) ? 2 : bi;
        bi = (s1 == bm) ? 1 : bi;
        bi = (s0 == bm) ? 0 : bi;
        nv[j] = bm + elt(X, s * KK + j);
        bits |= (uint32_t)bi << (3 * j);
      }
#pragma unroll
      for (int j = 0; j < KK; ++j) a[j] = nv[j];
      w[s >> 1] |= bits << ((s & 1) << 4);
    }
  }
  if (blk8 < len) *(uint4*)(bpb + blk8) = make_uint4(w[0], w[1], w[2], w[3]);
}

// ---------------- forward (linear space): one 8-step block ----------------
__device__ __forceinline__ void fwd_block(const Blk& X, int blk, int len,
                                          const float (&W)[KK][KK],
                                          float (&p)[KK], float& Cacc) {
  const int blk8 = blk * BS;
#pragma unroll
  for (int s = 0; s < BS; ++s) {
    const int t = blk8 + s;
    if (s == 0 && blk == 0) {
#pragma unroll
      for (int j = 0; j < KK; ++j) p[j] = __expf(elt(X, j));
    } else if (t < len) {
      float E[KK];
#pragma unroll
      for (int j = 0; j < KK; ++j) E[j] = __expf(elt(X, s * KK + j));
      float np_[KK];
#pragma unroll
      for (int j = 0; j < KK; ++j) {
        float acc = p[0] * W[0][j];
        acc = fmaf(p[1], W[1][j], acc);
        acc = fmaf(p[2], W[2][j], acc);
        acc = fmaf(p[3], W[3][j], acc);
        acc = fmaf(p[4], W[4][j], acc);
        np_[j] = acc * E[j];
      }
#pragma unroll
      for (int j = 0; j < KK; ++j) p[j] = np_[j];
    }
  }
  // renorm once per block (representation-neutral: safe for frozen lanes)
  const float m = fmaxf(fmaxf(fmaxf(p[0], p[1]), fmaxf(p[2], p[3])), p[4]);
  const float r = 1.0f / m;
#pragma unroll
  for (int j = 0; j < KK; ++j) p[j] *= r;
  Cacc += __logf(m);
}

// ---------------- unary/binary score: one 8-step block ----------------
__device__ __forceinline__ void sc_block(const TBlk& TB, int blk, int len,
                                         const float* __restrict__ prow,
                                         const float* __restrict__ trans,
                                         float& unary, float& binary, int& pt) {
  const int blk8 = blk * BS;
#pragma unroll
  for (int s = 0; s < BS; ++s) {
    const int t = blk8 + s;
    const int ct = telt(TB, s);
    if (t < len) {
      unary += prow[t * KK + ct];
      if (t >= 1) binary += trans[pt * KK + ct];
      pt = ct;
    }
  }
}

// ---------------------------------------------------------------------------
// One block = 192 threads = 3 waves over the same 64 batches:
//   wave 0: Viterbi scan + backtrace + zero-fill
//   wave 1: forward (linear-space logsumexp) -> log_norm, writes ll
//   wave 2: unary+binary gather -> LDS
// Waves barrier-lock per 8-step block so all three stream the same pot lines
// through L1. Barrier counts match across roles (nblk + 1 each).
// ---------------------------------------------------------------------------
__launch_bounds__(192, 1)
__global__ void crf_fused_kernel(const float* __restrict__ pot,
                                 const float* __restrict__ trans,
                                 const int* __restrict__ lens,
                                 const int* __restrict__ tags,
                                 float* __restrict__ out,
                                 uint16_t* __restrict__ bp,
                                 int B, int T) {
  __shared__ float s_ub[64];
  const int lane = threadIdx.x & 63;
  const int role = threadIdx.x >> 6;
  const int b = blockIdx.x * 64 + lane;
  const int len = lens[b];
  const float* __restrict__ prow = pot + (size_t)b * T * KK;
  const float4* __restrict__ p4 = (const float4*)prow;

  int ml = len;
#pragma unroll
  for (int d = 1; d < 64; d <<= 1) ml = max(ml, __shfl_xor(ml, d));
  const int nblk = (ml + BS - 1) / BS;      // wave-uniform, same for all roles
  const int NBm1 = T / BS - 1;              // last valid block index (63)

  if (role == 0) {
    // ---------------- Viterbi ----------------
    float tr[KK][KK];
#pragma unroll
    for (int i = 0; i < KK; ++i)
#pragma unroll
      for (int j = 0; j < KK; ++j) tr[i][j] = trans[i * KK + j];
    float a[KK];
    uint16_t* __restrict__ bpb = bp + (size_t)b * T;
    Blk A, Bb, C;
    loadBlk(A, p4);
    loadBlk(Bb, p4 + 10 * min(1, NBm1));
    loadBlk(C, p4 + 10 * min(2, NBm1));
    int blk = 0;
    while (true) {
      __syncthreads();
      vit_block(A, blk, len, tr, a, bpb);
      if (++blk == nblk) break;
      loadBlk(A, p4 + 10 * min(blk + 2, NBm1));
      __syncthreads();
      vit_block(Bb, blk, len, tr, a, bpb);
      if (++blk == nblk) break;
      loadBlk(Bb, p4 + 10 * min(blk + 2, NBm1));
      __syncthreads();
      vit_block(C, blk, len, tr, a, bpb);
      if (++blk == nblk) break;
      loadBlk(C, p4 + 10 * min(blk + 2, NBm1));
    }
    // final alpha argmax (first-max)
    const float bm = fmaxf(fmaxf(fmaxf(a[0], a[1]), fmaxf(a[2], a[3])), a[4]);
    int last = 4;
    last = (a[3] == bm) ? 3 : last;
    last = (a[2] == bm) ? 2 : last;
    last = (a[1] == bm) ? 1 : last;
    last = (a[0] == bm) ? 0 : last;
    __syncthreads();   // final barrier (pairs with other roles)
    // ---------------- backtrace (loads independent of tag chain) ----------
    float* __restrict__ orow = out + (size_t)b * T;
    orow[len - 1] = (float)last;
    int tag = last;
    const uint4* __restrict__ bq = (const uint4*)bpb;
    uint4 wv = bq[nblk - 1];
    for (int bi2 = nblk - 1; bi2 >= 0; --bi2) {
      const uint4 nx = bq[bi2 > 0 ? bi2 - 1 : 0];   // prefetch next block down
      const int t8 = bi2 * BS;
#pragma unroll
      for (int s = BS - 1; s >= 0; --s) {
        const int t = t8 + s;
        const uint32_t w = (s >> 1) == 0 ? wv.x : (s >> 1) == 1 ? wv.y
                         : (s >> 1) == 2 ? wv.z : wv.w;
        if (t >= 1 && t < len) {
          const int pv = (int)((w >> ((3 * tag) + ((s & 1) << 4))) & 7u);
          orow[t - 1] = (float)pv;
          tag = pv;
        }
      }
      wv = nx;
    }
    // zero tail [len, T)
    int t = len;
    while ((t & 3) && t < T) { orow[t] = 0.0f; ++t; }
    const float4 z4 = make_float4(0.f, 0.f, 0.f, 0.f);
    for (; t < T; t += 4) *(float4*)(orow + t) = z4;

  } else if (role == 1) {
    // ---------------- forward ----------------
    float W[KK][KK];
#pragma unroll
    for (int i = 0; i < KK; ++i)
#pragma unroll
      for (int j = 0; j < KK; ++j) W[i][j] = __expf(trans[i * KK + j]);
    float p[KK];
    float Cacc = 0.0f;
    Blk A, Bb, C;
    loadBlk(A, p4);
    loadBlk(Bb, p4 + 10 * min(1, NBm1));
    loadBlk(C, p4 + 10 * min(2, NBm1));
    int blk = 0;
    while (true) {
      __syncthreads();
      fwd_block(A, blk, len, W, p, Cacc);
      if (++blk == nblk) break;
      loadBlk(A, p4 + 10 * min(blk + 2, NBm1));
      __syncthreads();
      fwd_block(Bb, blk, len, W, p, Cacc);
      if (++blk == nblk) break;
      loadBlk(Bb, p4 + 10 * min(blk + 2, NBm1));
      __syncthreads();
      fwd_block(C, blk, len, W, p, Cacc);
      if (++blk == nblk) break;
      loadBlk(C, p4 + 10 * min(blk + 2, NBm1));
    }
    const float zsum = p[0] + p[1] + p[2] + p[3] + p[4];
    const float logZ = Cacc + __logf(zsum);
    __syncthreads();   // final barrier: s_ub ready
    out[(size_t)B * T + b] = s_ub[lane] - logZ;

  } else {
    // ---------------- unary + binary score ----------------
    const int* __restrict__ tg = tags + (size_t)b * T;
    float unary = 0.0f, binary = 0.0f;
    int pt = 0;
    TBlk A, Bb, C;
    loadTBlk(A, tg, 0);
    loadTBlk(Bb, tg, BS * min(1, NBm1));
    loadTBlk(C, tg, BS * min(2, NBm1));
    int blk = 0;
    while (true) {
      __syncthreads();
      sc_block(A, blk, len, prow, trans, unary, binary, pt);
      if (++blk == nblk) break;
      loadTBlk(A, tg, BS * min(blk + 2, NBm1));
      __syncthreads();
      sc_block(Bb, blk, len, prow, trans, unary, binary, pt);
      if (++blk == nblk) break;
      loadTBlk(Bb, tg, BS * min(blk + 2, NBm1));
      __syncthreads();
      sc_block(C, blk, len, prow, trans, unary, binary, pt);
      if (++blk == nblk) break;
      loadTBlk(C, tg, BS * min(blk + 2, NBm1));
    }
    s_ub[lane] = unary + binary;
    __syncthreads();   // final barrier
  }
}

// ---------------------------------------------------------------------------
extern "C" void kernel_launch(void* const* d_in, const int* in_sizes, int n_in,
                              void* d_out, int out_size, void* d_ws, size_t ws_size,
                              hipStream_t stream) {
  const float* pot   = (const float*)d_in[0];
  const float* trans = (const float*)d_in[1];
  const int*   lens  = (const int*)d_in[2];
  const int*   tags  = (const int*)d_in[3];
  float* out = (float*)d_out;

  const int B = in_sizes[2];
  const int T = in_sizes[3] / B;   // 512

  uint16_t* bp = (uint16_t*)d_ws;  // B*T*2 = 8 MB backpointer scratch

  crf_fused_kernel<<<B / 64, 192, 0, stream>>>(pot, trans, lens, tags, out, bp, B, T);
}

// Round 3
// 162.644 us; speedup vs baseline: 1.6389x; 1.1233x over previous
//
#include <hip/hip_runtime.h>
#include <stdint.h>

#define KK 5
#define BS 8
#define DPITCH 516   // bytes per decoded-staging row: 129 words, 129%32==1 -> conflict-free

struct Blk { float4 q[10]; };        // 8 steps x 5 floats
struct TBlk { int4 lo, hi; };        // 8 tags

// k must be compile-time (called from fully unrolled loops)
__device__ __forceinline__ float elt(const Blk& bb, int k) {
  const float4 v = bb.q[k >> 2];
  const int m = k & 3;
  return m == 0 ? v.x : (m == 1 ? v.y : (m == 2 ? v.z : v.w));
}
__device__ __forceinline__ int telt(const TBlk& tb, int s) {   // s compile-time
  const int4 v = (s < 4) ? tb.lo : tb.hi;
  const int m = s & 3;
  return m == 0 ? v.x : (m == 1 ? v.y : (m == 2 ? v.z : v.w));
}
// runtime ct in 0..4, pv statically indexed -> 4 cndmask, no scratch
__device__ __forceinline__ float sel5(const float (&pv)[KK], int ct) {
  float u = pv[0];
  u = (ct == 1) ? pv[1] : u;
  u = (ct == 2) ? pv[2] : u;
  u = (ct == 3) ? pv[3] : u;
  u = (ct == 4) ? pv[4] : u;
  return u;
}
__device__ __forceinline__ void loadBlk(Blk& dst, const float4* __restrict__ src) {
#pragma unroll
  for (int q = 0; q < 10; ++q) dst.q[q] = src[q];
}
__device__ __forceinline__ void loadTBlk(TBlk& dst, const int* __restrict__ tg, int blk8) {
  dst.lo = *(const int4*)(tg + blk8);
  dst.hi = *(const int4*)(tg + blk8 + 4);
}

// ---------------- Viterbi: one 8-step block ----------------
__device__ __forceinline__ void vit_block(const Blk& X, int blk, int len,
                                          const float (&tr)[KK][KK],
                                          float (&a)[KK],
                                          uint16_t* __restrict__ bpb) {
  const int blk8 = blk * BS;
  uint32_t w[4] = {0u, 0u, 0u, 0u};
#pragma unroll
  for (int s = 0; s < BS; ++s) {
    const int t = blk8 + s;
    if (s == 0 && blk == 0) {
#pragma unroll
      for (int j = 0; j < KK; ++j) a[j] = elt(X, j);
    } else {
      const bool act = (t < len);
      float nv[KK];
      uint32_t bits = 0;
#pragma unroll
      for (int j = 0; j < KK; ++j) {
        const float s0 = a[0] + tr[0][j];
        const float s1 = a[1] + tr[1][j];
        const float s2 = a[2] + tr[2][j];
        const float s3 = a[3] + tr[3][j];
        const float s4 = a[4] + tr[4][j];
        const float bm = fmaxf(fmaxf(fmaxf(s0, s1), fmaxf(s2, s3)), s4);
        int bi = 4;                       // first-max tie-break (== jnp.argmax)
        bi = (s3 == bm) ? 3 : bi;
        bi = (s2 == bm) ? 2 : bi;
        bi = (s1 == bm) ? 1 : bi;
        bi = (s0 == bm) ? 0 : bi;
        nv[j] = bm + elt(X, s * KK + j);
        bits |= (uint32_t)bi << (3 * j);
      }
      if (act) {
#pragma unroll
        for (int j = 0; j < KK; ++j) a[j] = nv[j];
        w[s >> 1] |= bits << ((s & 1) << 4);
      }
    }
  }
  if (blk8 < len) *(uint4*)(bpb + blk8) = make_uint4(w[0], w[1], w[2], w[3]);
}

// ---------------- forward + score: one 8-step block ----------------
__device__ __forceinline__ void fwd_block(const Blk& X, const TBlk& TB, int blk, int len,
                                          const float (&W)[KK][KK],
                                          const float* __restrict__ s_trans,
                                          float (&p)[KK], float& Cacc,
                                          float& unary, float& binary, int& pt) {
  const int blk8 = blk * BS;
#pragma unroll
  for (int s = 0; s < BS; ++s) {
    const int t = blk8 + s;
    float pv[KK];
#pragma unroll
    for (int j = 0; j < KK; ++j) pv[j] = elt(X, s * KK + j);
    if (s == 0 && blk == 0) {
#pragma unroll
      for (int j = 0; j < KK; ++j) p[j] = __expf(pv[j]);
      pt = telt(TB, 0);
      unary = sel5(pv, pt);
    } else {
      const bool act = (t < len);
      float E[KK];
#pragma unroll
      for (int j = 0; j < KK; ++j) E[j] = __expf(pv[j]);
      float np_[KK];
#pragma unroll
      for (int j = 0; j < KK; ++j) {
        float acc = p[0] * W[0][j];
        acc = fmaf(p[1], W[1][j], acc);
        acc = fmaf(p[2], W[2][j], acc);
        acc = fmaf(p[3], W[3][j], acc);
        acc = fmaf(p[4], W[4][j], acc);
        np_[j] = acc * E[j];
      }
      const int ct = telt(TB, s);
      const float u = sel5(pv, ct);
      const float bnr = s_trans[pt * KK + ct];   // LDS, always-safe address
      if (act) {
#pragma unroll
        for (int j = 0; j < KK; ++j) p[j] = np_[j];
        unary += u;
        binary += bnr;
        pt = ct;
      }
    }
  }
  // renorm once per block (representation-neutral; safe for frozen lanes)
  const float m = fmaxf(fmaxf(fmaxf(p[0], p[1]), fmaxf(p[2], p[3])), p[4]);
  const float r = 1.0f / m;
#pragma unroll
  for (int j = 0; j < KK; ++j) p[j] *= r;
  Cacc += __logf(m);
}

// ---------------------------------------------------------------------------
// 2*(B/64) blocks x 64 threads (1 wave each). role 0: Viterbi+backtrace+flush.
// role 1: forward+score -> log_likelihood. No barriers anywhere: prefetch
// loads stay in flight (compiler emits counted vmcnt at use).
// Blocks g and g+ngrp are 128 apart -> same XCD (128%8==0): pot L2 sharing.
// ---------------------------------------------------------------------------
__launch_bounds__(64)
__global__ void crf_kernel(const float* __restrict__ pot,
                           const float* __restrict__ trans,
                           const int* __restrict__ lens,
                           const int* __restrict__ tags,
                           float* __restrict__ out,
                           uint16_t* __restrict__ bp,
                           int B, int T) {
  __shared__ float s_trans[KK * KK];
  __shared__ uint8_t s_dec[64 * DPITCH];   // ~33 KB decoded staging (role 0 only)
  const int lane = threadIdx.x;
  const int ngrp = B / 64;
  const int role = (blockIdx.x >= ngrp) ? 1 : 0;
  const int grp  = blockIdx.x - role * ngrp;
  const int b    = grp * 64 + lane;
  const int len  = lens[b];
  const float4* __restrict__ p4 = (const float4*)(pot + (size_t)b * T * KK);

  if (lane < KK * KK) s_trans[lane] = trans[lane];

  int ml = len;
#pragma unroll
  for (int d = 1; d < 64; d <<= 1) ml = max(ml, __shfl_xor(ml, d));
  const int nblk = (ml + BS - 1) / BS;      // wave-uniform
  const int NBm1 = T / BS - 1;

  if (role == 0) {
    // ================= Viterbi scan =================
    float tr[KK][KK];
#pragma unroll
    for (int i = 0; i < KK; ++i)
#pragma unroll
      for (int j = 0; j < KK; ++j) tr[i][j] = trans[i * KK + j];  // uniform -> s_load
    float a[KK];
    uint16_t* __restrict__ bpb = bp + (size_t)b * T;
    Blk A, Bb, C;
    loadBlk(A, p4);
    loadBlk(Bb, p4 + 10 * min(1, NBm1));
    loadBlk(C, p4 + 10 * min(2, NBm1));
    int blk = 0;
    while (true) {
      vit_block(A, blk, len, tr, a, bpb);
      if (++blk == nblk) break;
      loadBlk(A, p4 + 10 * min(blk + 2, NBm1));
      vit_block(Bb, blk, len, tr, a, bpb);
      if (++blk == nblk) break;
      loadBlk(Bb, p4 + 10 * min(blk + 2, NBm1));
      vit_block(C, blk, len, tr, a, bpb);
      if (++blk == nblk) break;
      loadBlk(C, p4 + 10 * min(blk + 2, NBm1));
    }
    // final alpha argmax (first-max)
    const float bm = fmaxf(fmaxf(fmaxf(a[0], a[1]), fmaxf(a[2], a[3])), a[4]);
    int last = 4;
    last = (a[3] == bm) ? 3 : last;
    last = (a[2] == bm) ? 2 : last;
    last = (a[1] == bm) ? 1 : last;
    last = (a[0] == bm) ? 0 : last;

    // ================= backtrace (6-deep bp prefetch, stage u8 into LDS) ====
    s_dec[lane * DPITCH + (len - 1)] = (uint8_t)last;
    int tag = last;
    const uint4* __restrict__ bq = (const uint4*)bpb;
    int i = nblk - 1;
    uint4 v0 = bq[i];
    uint4 v1 = bq[max(i - 1, 0)];
    uint4 v2 = bq[max(i - 2, 0)];
    uint4 v3 = bq[max(i - 3, 0)];
    uint4 v4 = bq[max(i - 4, 0)];
    uint4 v5 = bq[max(i - 5, 0)];
    while (i >= 0) {
      const int t8 = i * BS;
#pragma unroll
      for (int s = BS - 1; s >= 0; --s) {
        const int t = t8 + s;
        if (t >= 1 && t < len) {
          const uint32_t w = (s >> 1) == 0 ? v0.x : (s >> 1) == 1 ? v0.y
                           : (s >> 1) == 2 ? v0.z : v0.w;
          const int pv = (int)((w >> ((3 * tag) + ((s & 1) << 4))) & 7u);
          s_dec[lane * DPITCH + (t - 1)] = (uint8_t)pv;
          tag = pv;
        }
      }
      v0 = v1; v1 = v2; v2 = v3; v3 = v4; v4 = v5;
      v5 = bq[max(i - 6, 0)];
      --i;
    }
    // ================= coalesced flush: LDS u8 -> float rows ================
    for (int r = 0; r < 64; ++r) {
      const int lr = __shfl(len, r);
      const uint8_t* rowp = s_dec + r * DPITCH + lane * 8;
      const uint32_t w0 = *(const uint32_t*)(rowp);
      const uint32_t w1 = *(const uint32_t*)(rowp + 4);
      const int t0 = lane * 8;
      float f[8];
#pragma unroll
      for (int k = 0; k < 8; ++k) {
        const uint32_t byte = ((k < 4 ? w0 >> (8 * k) : w1 >> (8 * (k - 4))) & 0xffu);
        f[k] = (t0 + k < lr) ? (float)byte : 0.0f;
      }
      float* orow = out + (size_t)(grp * 64 + r) * T + t0;
      *(float4*)(orow)     = make_float4(f[0], f[1], f[2], f[3]);
      *(float4*)(orow + 4) = make_float4(f[4], f[5], f[6], f[7]);
    }

  } else {
    // ================= forward (linear-space) + unary/binary score ==========
    float W[KK][KK];
#pragma unroll
    for (int i = 0; i < KK; ++i)
#pragma unroll
      for (int j = 0; j < KK; ++j) W[i][j] = __expf(trans[i * KK + j]);
    float p[KK];
    float Cacc = 0.0f, unary = 0.0f, binary = 0.0f;
    int pt = 0;
    const int* __restrict__ tg = tags + (size_t)b * T;
    Blk A, Bb, C;
    TBlk TA, TBb, TC;
    loadBlk(A, p4);                       loadTBlk(TA, tg, 0);
    loadBlk(Bb, p4 + 10 * min(1, NBm1)); loadTBlk(TBb, tg, BS * min(1, NBm1));
    loadBlk(C, p4 + 10 * min(2, NBm1));  loadTBlk(TC, tg, BS * min(2, NBm1));
    int blk = 0;
    while (true) {
      fwd_block(A, TA, blk, len, W, s_trans, p, Cacc, unary, binary, pt);
      if (++blk == nblk) break;
      loadBlk(A, p4 + 10 * min(blk + 2, NBm1)); loadTBlk(TA, tg, BS * min(blk + 2, NBm1));
      fwd_block(Bb, TBb, blk, len, W, s_trans, p, Cacc, unary, binary, pt);
      if (++blk == nblk) break;
      loadBlk(Bb, p4 + 10 * min(blk + 2, NBm1)); loadTBlk(TBb, tg, BS * min(blk + 2, NBm1));
      fwd_block(C, TC, blk, len, W, s_trans, p, Cacc, unary, binary, pt);
      if (++blk == nblk) break;
      loadBlk(C, p4 + 10 * min(blk + 2, NBm1)); loadTBlk(TC, tg, BS * min(blk + 2, NBm1));
    }
    const float zsum = p[0] + p[1] + p[2] + p[3] + p[4];
    const float logZ = Cacc + __logf(zsum);
    out[(size_t)B * T + b] = unary + binary - logZ;
  }
}

// ---------------------------------------------------------------------------
extern "C" void kernel_launch(void* const* d_in, const int* in_sizes, int n_in,
                              void* d_out, int out_size, void* d_ws, size_t ws_size,
                              hipStream_t stream) {
  const float* pot   = (const float*)d_in[0];
  const float* trans = (const float*)d_in[1];
  const int*   lens  = (const int*)d_in[2];
  const int*   tags  = (const int*)d_in[3];
  float* out = (float*)d_out;

  const int B = in_sizes[2];
  const int T = in_sizes[3] / B;   // 512

  uint16_t* bp = (uint16_t*)d_ws;  // B*T*2 = 8 MB backpointer scratch

  crf_kernel<<<2 * (B / 64), 64, 0, stream>>>(pot, trans, lens, tags, out, bp, B, T);
}

// Round 4
// 91.895 us; speedup vs baseline: 2.9006x; 1.7699x over previous
//
#include <hip/hip_runtime.h>
#include <stdint.h>

#define KK 5
#define TT 512

// ---- cross-lane helpers (8-lane groups; groups never straddle the 32-lane
// ds_swizzle boundary since 8 | 32) ----
template<int P>
__device__ __forceinline__ float swzf(float v) {
  return __int_as_float(__builtin_amdgcn_ds_swizzle(__float_as_int(v), P));
}
template<int P>
__device__ __forceinline__ int swzi(int v) {
  return __builtin_amdgcn_ds_swizzle(v, P);
}
// broadcast lane (group*8 + i):  offset = (i<<5) | 0x18
#define BC0 0x018
#define BC1 0x038
#define BC2 0x058
#define BC3 0x078
#define BC4 0x098
// xor-butterfly within group: offset = (m<<10) | 0x1F
#define X1 0x041F
#define X2 0x081F
#define X4 0x101F

// load one 8-step column block: element t for t = 8k+1 .. 8k+8 (clamped at 511)
__device__ __forceinline__ void loadCol(float (&d)[8], const float* __restrict__ colp, int k) {
  const int t0 = k * 8 + 1;
  if (k < 63) {
#pragma unroll
    for (int s = 0; s < 8; ++s) d[s] = colp[(t0 + s) * KK];
  } else {
#pragma unroll
    for (int s = 0; s < 8; ++s) d[s] = colp[min(t0 + s, TT - 1) * KK];
  }
}

// ---------------- Viterbi: 8 scan steps + in-block path map ----------------
__device__ __forceinline__ void vit_map_block(const float (&pv)[8], int k, int len_eff,
                                              const float (&trc)[KK], float& a,
                                              int jj, int g, int r,
                                              uint32_t* __restrict__ s_map) {
  uint32_t bits = 0;
#pragma unroll
  for (int s = 0; s < 8; ++s) {
    const float av0 = swzf<BC0>(a), av1 = swzf<BC1>(a), av2 = swzf<BC2>(a),
                av3 = swzf<BC3>(a), av4 = swzf<BC4>(a);
    const float s0 = av0 + trc[0], s1 = av1 + trc[1], s2 = av2 + trc[2],
                s3 = av3 + trc[3], s4 = av4 + trc[4];
    const float bm = fmaxf(fmaxf(fmaxf(s0, s1), fmaxf(s2, s3)), s4);
    int bi = 4;                      // first-max tie-break == jnp.argmax
    bi = (s3 == bm) ? 3 : bi;
    bi = (s2 == bm) ? 2 : bi;
    bi = (s1 == bm) ? 1 : bi;
    bi = (s0 == bm) ? 0 : bi;
    const int t = k * 8 + s + 1;
    const bool act = (t < len_eff);
    a = act ? (bm + pv[s]) : a;
    const int bie = act ? bi : jj;   // identity backpointer when frozen
    bits |= (uint32_t)bie << (3 * s);
  }
  // path map: assume exit tag jj at boundary t=8k+8, walk back through block.
  // dec bits [3s..3s+2] = decoded tag at position 8k+s; entry tag = dec & 7.
  int cur = jj;
  uint32_t dec = 0;
#pragma unroll
  for (int s = 7; s >= 0; --s) {
    const int w = __builtin_amdgcn_ds_bpermute(((g << 3) + cur) << 2, (int)bits);
    const int b3 = (w >> (3 * s)) & 7;
    dec |= (uint32_t)b3 << (3 * s);
    cur = b3;
  }
  if (r < 5) s_map[g * 321 + k * 5 + jj] = dec;
}

// ---------------- forward: 8 linear-space steps + renorm ----------------
__device__ __forceinline__ void fwd_block(const float (&pv)[8], int k, int len_eff,
                                          const float (&Wc)[KK], float& p, float& Cacc) {
#pragma unroll
  for (int s = 0; s < 8; ++s) {
    const float p0 = swzf<BC0>(p), p1 = swzf<BC1>(p), p2 = swzf<BC2>(p),
                p3 = swzf<BC3>(p), p4 = swzf<BC4>(p);
    const float u  = fmaf(p1, Wc[1], p0 * Wc[0]);
    const float v2 = fmaf(p3, Wc[3], p2 * Wc[2]);
    const float acc = fmaf(p4, Wc[4], u + v2);
    const float E = __expf(pv[s]);
    const int t = k * 8 + s + 1;
    const bool act = (t < len_eff);
    p = act ? (acc * E) : p;
  }
  float m = p;
  m = fmaxf(m, swzf<X1>(m));
  m = fmaxf(m, swzf<X2>(m));
  m = fmaxf(m, swzf<X4>(m));           // lanes r>=5 hold p=0: never the max (p>0 real)
  p *= (1.0f / m);
  Cacc += __logf(m);
}

// ---------------------------------------------------------------------------
// grid: 2*(B/8) blocks x 64 threads (1 wave). Each wave: 8 batches, 8 lanes
// per batch (5 compute tags, 3 aux). role: (blockIdx&8)!=0 -> forward+score,
// else Viterbi. Blocks u and u+8 share batches AND XCD (u%8 equal).
// ---------------------------------------------------------------------------
__launch_bounds__(64)
__global__ void crf_kernel(const float* __restrict__ pot,
                           const float* __restrict__ trans,
                           const int* __restrict__ lens,
                           const int* __restrict__ tags,
                           float* __restrict__ out,
                           int B, int T) {
  __shared__ uint32_t s_map[8 * 321];   // [g][k][j], stride 321 breaks bank alias
  __shared__ uint32_t s_chosen[8 * 65];
  const int lane = threadIdx.x;
  const int g = lane >> 3, r = lane & 7;
  const int jj = (r < 5) ? r : 4;
  const unsigned u = blockIdx.x;
  const int role = (u >> 3) & 1;
  const int idx = (int)((u & 7u) | ((u >> 4) << 3));
  const int b = idx * 8 + g;
  const int len = lens[b];
  const int len_eff = (r < 5) ? len : 0;
  const float* __restrict__ prow = pot + (size_t)b * (T * KK);
  const float* __restrict__ colp = prow + jj;

  int ml = len;
  ml = max(ml, __shfl_xor(ml, 8));
  ml = max(ml, __shfl_xor(ml, 16));
  ml = max(ml, __shfl_xor(ml, 32));
  const int nblk = (ml + 7) >> 3;       // covers position len-1 for all lanes

  if (role == 0) {
    // ========================= Viterbi =========================
    float trc[KK];
#pragma unroll
    for (int i = 0; i < KK; ++i) trc[i] = trans[i * KK + jj];
    float a = (r < 5) ? prow[jj] : -3.0e38f;

    float pA[8], pB[8], pC[8];
    loadCol(pA, colp, 0);
    loadCol(pB, colp, min(1, nblk - 1));
    loadCol(pC, colp, min(2, nblk - 1));
    int blk = 0;
    while (true) {
      vit_map_block(pA, blk, len_eff, trc, a, jj, g, r, s_map);
      if (++blk == nblk) break;
      loadCol(pA, colp, min(blk + 2, nblk - 1));
      vit_map_block(pB, blk, len_eff, trc, a, jj, g, r, s_map);
      if (++blk == nblk) break;
      loadCol(pB, colp, min(blk + 2, nblk - 1));
      vit_map_block(pC, blk, len_eff, trc, a, jj, g, r, s_map);
      if (++blk == nblk) break;
      loadCol(pC, colp, min(blk + 2, nblk - 1));
    }
    // final argmax (first-max) over lanes r<5 of each group
    float bm = a;
    bm = fmaxf(bm, swzf<X1>(bm));
    bm = fmaxf(bm, swzf<X2>(bm));
    bm = fmaxf(bm, swzf<X4>(bm));
    int cand = (r < 5 && a == bm) ? r : 7;
    cand = min(cand, swzi<X1>(cand));
    cand = min(cand, swzi<X2>(cand));
    cand = min(cand, swzi<X4>(cand));
    const int last = cand;

    __syncthreads();                    // all map writes visible
    if (r == 0) {
      int tag = last;
      for (int k2 = nblk - 1; k2 >= 0; --k2) {
        const uint32_t w = s_map[g * 321 + k2 * 5 + tag];
        s_chosen[g * 65 + k2] = w;
        tag = (int)(w & 7u);
      }
    }
    __syncthreads();                    // chosen visible to all lanes

    // coalesced decoded write: lane r covers blocks kk*8+r
    float* __restrict__ orow = out + (size_t)b * T;
#pragma unroll
    for (int kk = 0; kk < 8; ++kk) {
      const int k2 = kk * 8 + r;
      const uint32_t w = s_chosen[g * 65 + k2];
      const int base = k2 * 8;
      float f[8];
#pragma unroll
      for (int pI = 0; pI < 8; ++pI)
        f[pI] = (base + pI < len) ? (float)((w >> (3 * pI)) & 7u) : 0.0f;
      *(float4*)(orow + base)     = make_float4(f[0], f[1], f[2], f[3]);
      *(float4*)(orow + base + 4) = make_float4(f[4], f[5], f[6], f[7]);
    }

  } else {
    // ==================== forward + score ====================
    const float trv = trans[min(lane, 24)];   // distributed 5x5 table
    // ---- score prologue: lane r sums t in [r*64, r*64+64) of its batch ----
    const int* __restrict__ tgrow = tags + (size_t)b * T;
    float sc = 0.0f;
    {
      const int t0 = r * 64;
      int ptag = (t0 == 0) ? 0 : tgrow[t0 - 1];
#pragma unroll 2
      for (int q = 0; q < 16; ++q) {
        const int4 tq = *(const int4*)(tgrow + t0 + q * 4);
#pragma unroll
        for (int m = 0; m < 4; ++m) {
          const int t = t0 + q * 4 + m;
          const int ct = (m == 0) ? tq.x : (m == 1) ? tq.y : (m == 2) ? tq.z : tq.w;
          const float uadd = prow[t * KK + ct];
          const float badd = __int_as_float(__builtin_amdgcn_ds_bpermute(
              (ptag * KK + ct) << 2, __float_as_int(trv)));
          const float contrib = uadd + ((t >= 1) ? badd : 0.0f);
          sc += (t < len) ? contrib : 0.0f;
          ptag = ct;
        }
      }
    }
    sc += swzf<X1>(sc);
    sc += swzf<X2>(sc);
    sc += swzf<X4>(sc);                  // group total (lanes each own a chunk)

    // ---- forward scan (linear space) ----
    float Wc[KK];
#pragma unroll
    for (int i = 0; i < KK; ++i) Wc[i] = __expf(trans[i * KK + jj]);
    float p = (r < 5) ? __expf(prow[jj]) : 0.0f;
    float Cacc = 0.0f;

    float pA[8], pB[8], pC[8];
    loadCol(pA, colp, 0);
    loadCol(pB, colp, min(1, nblk - 1));
    loadCol(pC, colp, min(2, nblk - 1));
    int blk = 0;
    while (true) {
      fwd_block(pA, blk, len_eff, Wc, p, Cacc);
      if (++blk == nblk) break;
      loadCol(pA, colp, min(blk + 2, nblk - 1));
      fwd_block(pB, blk, len_eff, Wc, p, Cacc);
      if (++blk == nblk) break;
      loadCol(pB, colp, min(blk + 2, nblk - 1));
      fwd_block(pC, blk, len_eff, Wc, p, Cacc);
      if (++blk == nblk) break;
      loadCol(pC, colp, min(blk + 2, nblk - 1));
    }
    float ps = p;
    ps += swzf<X1>(ps);
    ps += swzf<X2>(ps);
    ps += swzf<X4>(ps);                  // lanes r>=5 contribute 0
    const float logZ = Cacc + __logf(ps);
    if (r == 0) out[(size_t)B * T + b] = sc - logZ;
  }
}

// ---------------------------------------------------------------------------
extern "C" void kernel_launch(void* const* d_in, const int* in_sizes, int n_in,
                              void* d_out, int out_size, void* d_ws, size_t ws_size,
                              hipStream_t stream) {
  const float* pot   = (const float*)d_in[0];
  const float* trans = (const float*)d_in[1];
  const int*   lens  = (const int*)d_in[2];
  const int*   tags  = (const int*)d_in[3];
  float* out = (float*)d_out;

  const int B = in_sizes[2];
  const int T = in_sizes[3] / B;   // 512

  const int nblocks = 2 * (B / 8);  // 2048
  crf_kernel<<<nblocks, 64, 0, stream>>>(pot, trans, lens, tags, out, B, T);
}